// Round 9
// baseline (232.474 us; speedup 1.0000x reference)
//
#include <hip/hip_runtime.h>
#include <hip/hip_bf16.h>
#include <stdint.h>

#define Bsz   16384
#define Tt    79
#define Hh    256
#define Dd    256
#define KP    272    // padded K: 256 h-cols + 3 x rows + 1 bias row + 12 zero pad
#define LROW  280    // LDS row stride in bf16 (560 B)
#define NTILE 32     // batch rows per TILE; block owns 2 tiles = 64 rows
#define THR   256    // 4 waves; wave w = m-quarter for BOTH tiles

typedef __attribute__((ext_vector_type(8)))  short  short8;
typedef __attribute__((ext_vector_type(4)))  float  float4_;
typedef __attribute__((ext_vector_type(16))) float  float16_;

__device__ __forceinline__ unsigned short f2bf(float f){
  unsigned u = __float_as_uint(f);
  u += 0x7fffu + ((u >> 16) & 1u);      // RNE
  return (unsigned short)(u >> 16);
}
// HW packed f32x2 -> bf16x2 (RNE); no builtin on gfx950 (round-5: -11 us).
__device__ __forceinline__ unsigned pk2(float a, float b){
  unsigned r;
  asm("v_cvt_pk_bf16_f32 %0, %1, %2" : "=v"(r) : "v"(a), "v"(b));
  return r;
}

#define MFMA32(A,B,C) __builtin_amdgcn_mfma_f32_32x32x16_bf16((A),(B),(C),0,0,0)
#define SGB(m,n) __builtin_amdgcn_sched_group_barrier((m),(n),0)

__global__ void build_tables(const float* __restrict__ W_in,
                             const float* __restrict__ U,
                             const float* __restrict__ b_rnn,
                             const float* __restrict__ W_d,
                             const float* __restrict__ b_d,
                             unsigned short* __restrict__ Ut,
                             unsigned short* __restrict__ Wdt){
  const int TBL = 256 * KP;
  int idx = blockIdx.x * 256 + threadIdx.x;
  if (idx >= 2 * TBL) return;
  int tb  = idx / TBL;
  int rem = idx - tb * TBL;
  int m = rem / KP;
  int k = rem - m * KP;
  float v = 0.f;
  if (tb == 0){
    if      (k < 256) v = U[k * 256 + m];
    else if (k < 259) v = W_in[(k - 256) * 256 + m];
    else if (k == 259) v = b_rnn[m];
  } else {
    if      (k < 256) v = W_d[k * 256 + m];
    else if (k == 259) v = b_d[m];
  }
  unsigned short o = f2bf(v);
  if (tb == 0) Ut[rem] = o; else Wdt[rem] = o;
}

// ROUND-9: DUAL-STREAM WAVES. Model from rounds 1-8: in-order issue means a
// wave stalled at an MFMA (pipe busy) cannot issue its later VALU; two
// phase-locked waves/SIMD interleave 1:1 in EVERY phase -> step = MFMA(2196)
// + VALU(1130) + tail(~700) ADDITIVE. Fix: one wave, TWO independent batch
// tiles P,Q. Program order interleaves P's relu/pack/write between Q's MFMA
// pairs, so every MFMA stall-gap has ready VALU ahead of the next MFMA.
// 256 blocks x 256 thr; LDS padded >80KB forces 1 block/CU (1 wave/SIMD,
// ~240 of 512 regs). sched_group_barrier pins the interleave pattern.
__global__ __launch_bounds__(THR, 1) void rnn_main(
    const float* __restrict__ x0,
    const float* __restrict__ x1,
    const float* __restrict__ x2,
    const unsigned short* __restrict__ Ut,
    const unsigned short* __restrict__ Wdt,
    float* __restrict__ out){
  __shared__ __align__(16) short hbuf[2][2][NTILE * LROW];  // [dbuf][tile]
  __shared__ float ldspad[2700];   // pad LDS to 82,480 B: >81,920 -> 1 block/CU

  const int tid  = threadIdx.x;
  const int lane = tid & 63;
  const int wm   = tid >> 6;        // m-quarter 0..3
  const int nrow = lane & 31;       // B operand / C col: batch row
  const int hi   = lane >> 5;       // k-half for A/B fragments
  const int hi8  = hi * 8;
  const int hi4  = hi * 4;
  const int bbase = blockIdx.x * (2 * NTILE);

  // keep the pad allocated (address observed; never executed path not needed)
  asm volatile("" :: "v"((unsigned)(size_t)(void*)ldspad));

  // ---- zero all 4 LDS h-buffers ----
  {
    int4* p = (int4*)&hbuf[0][0][0];
    const int tot = 2 * 2 * NTILE * LROW * 2 / 16;
    int4 z = make_int4(0, 0, 0, 0);
    for (int i = tid; i < tot; i += THR) p[i] = z;
  }
  __syncthreads();

  // bias row (k=259) = 1.0 bf16 in all 4 buffers (never overwritten)
  if (tid < NTILE){
    hbuf[0][0][tid * LROW + 259] = (short)0x3F80;
    hbuf[0][1][tid * LROW + 259] = (short)0x3F80;
    hbuf[1][0][tid * LROW + 259] = (short)0x3F80;
    hbuf[1][1][tid * LROW + 259] = (short)0x3F80;
  }

  // x staging: wave 0 stages tile P, wave 1 stages tile Q (32 rows each)
  const bool stager = (wm < 2) && (lane < NTILE);
  const int  sn  = lane & (NTILE - 1);
  const int  sgb = bbase + wm * NTILE + sn;   // global batch row
  if (stager){
    int tr = Tt - 1;
    float a = x0[sgb * Tt + tr];
    float b = x1[sgb * Tt + tr];
    float c = x2[sgb * Tt + tr];
    *(unsigned*)&hbuf[0][wm][sn * LROW + 256] = pk2(a, b);
    hbuf[0][wm][sn * LROW + 258] = (short)f2bf(c);
  }

  // ---- preload A fragments (shared by P and Q): 2 mt x 17 kt = 136 regs ----
  short8 afr[2][17];
  #pragma unroll
  for (int mt = 0; mt < 2; ++mt){
    const unsigned short* p = Ut + (wm * 64 + mt * 32 + nrow) * KP + hi8;
    #pragma unroll
    for (int kt = 0; kt < 17; ++kt){
      afr[mt][kt] = *(const short8*)(p + kt * 16);
    }
  }

  __syncthreads();

  const float16_ zz = {0.f,0.f,0.f,0.f,0.f,0.f,0.f,0.f,
                       0.f,0.f,0.f,0.f,0.f,0.f,0.f,0.f};
  float16_ accP[2], accQ[2];

  // ---- 79 recurrence steps, ONE barrier each ----
  #pragma unroll 1
  for (int t = 0; t < Tt; ++t){
    const int cb = t & 1, nb = (t + 1) & 1;
    const short* rbaseP = &hbuf[cb][0][nrow * LROW + hi8];
    const short* rbaseQ = &hbuf[cb][1][nrow * LROW + hi8];
    short* hwP = &hbuf[nb][0][0];
    short* hwQ = &hbuf[nb][1][0];

    // x prefetch for step t+1 (latency hidden under the whole step)
    float xa = 0.f, xb = 0.f, xc = 0.f;
    if (stager && t < Tt - 1){
      int tr = Tt - 2 - t;
      xa = x0[sgb * Tt + tr];
      xb = x1[sgb * Tt + tr];
      xc = x2[sgb * Tt + tr];
    }

    // ---- stream P: full K-loop (compiler pipelines the reads) ----
    __builtin_amdgcn_s_setprio(1);
    #pragma unroll
    for (int kt = 0; kt < 17; ++kt){
      short8 b = *(const short8*)(rbaseP + kt * 16);
      if (kt == 0){
        accP[0] = MFMA32(afr[0][0], b, zz);
        accP[1] = MFMA32(afr[1][0], b, zz);
      } else {
        accP[0] = MFMA32(afr[0][kt], b, accP[0]);
        accP[1] = MFMA32(afr[1][kt], b, accP[1]);
      }
    }

    // ---- stream Q K-loop, P's tail interleaved between MFMA pairs ----
    // TAILP(mt,q): relu+pack+write one quadrant of P's h(t+1).
    // C/D 32x32 layout: col=nrow, row m = 8*q + 4*hi + (reg&3)
#define QSTEP(kt) { short8 b = *(const short8*)(rbaseQ + (kt) * 16);           \
      accQ[0] = MFMA32(afr[0][kt], b, (kt) == 0 ? zz : accQ[0]);               \
      accQ[1] = MFMA32(afr[1][kt], b, (kt) == 0 ? zz : accQ[1]); }
#define TAILP(mt,q) { uint2 w;                                                 \
      w.x = pk2(fmaxf(accP[mt][4*(q)+0], 0.f), fmaxf(accP[mt][4*(q)+1], 0.f)); \
      w.y = pk2(fmaxf(accP[mt][4*(q)+2], 0.f), fmaxf(accP[mt][4*(q)+3], 0.f)); \
      *(uint2*)&hwP[nrow * LROW + wm * 64 + (mt) * 32 + 8 * (q) + hi4] = w; }
#define PIN() { SGB(0x100, 2); SGB(0x8, 4); SGB(0x2, 6); SGB(0x200, 1); }

    QSTEP(0)  QSTEP(1)  TAILP(0,0) PIN()
    QSTEP(2)  QSTEP(3)  TAILP(0,1) PIN()
    QSTEP(4)  QSTEP(5)  TAILP(0,2) PIN()
    QSTEP(6)  QSTEP(7)  TAILP(0,3) PIN()
    QSTEP(8)  QSTEP(9)  TAILP(1,0) PIN()
    QSTEP(10) QSTEP(11) TAILP(1,1) PIN()
    QSTEP(12) QSTEP(13) TAILP(1,2) PIN()
    QSTEP(14) QSTEP(15) TAILP(1,3) PIN()
    QSTEP(16)
    __builtin_amdgcn_s_setprio(0);

    // ---- stream Q tail ----
    #pragma unroll
    for (int mt = 0; mt < 2; ++mt){
      #pragma unroll
      for (int q = 0; q < 4; ++q){
        uint2 w;
        w.x = pk2(fmaxf(accQ[mt][4*q+0], 0.f), fmaxf(accQ[mt][4*q+1], 0.f));
        w.y = pk2(fmaxf(accQ[mt][4*q+2], 0.f), fmaxf(accQ[mt][4*q+3], 0.f));
        *(uint2*)&hwQ[nrow * LROW + wm * 64 + mt * 32 + 8 * q + hi4] = w;
      }
    }

    if (stager && t < Tt - 1){
      short* hwS = (wm == 0) ? hwP : hwQ;
      *(unsigned*)&hwS[sn * LROW + 256] = pk2(xa, xb);
      hwS[sn * LROW + 258] = (short)f2bf(xc);
    }

    __syncthreads();   // h(t+1)/x(t+1) for both tiles visible
  }

  // ---- epilogue: out^T = W_d^T h^T + b_d for both tiles ----
  #pragma unroll 1
  for (int tile = 0; tile < 2; ++tile){
    const short* hb = &hbuf[Tt & 1][tile][0];
    float16_ oacc[2];
    #pragma unroll
    for (int kt = 0; kt < 17; ++kt){
      short8 b  = *(const short8*)&hb[nrow * LROW + kt * 16 + hi8];
      short8 w0 = *(const short8*)(Wdt + (wm * 64 +  0 + nrow) * KP + kt * 16 + hi8);
      short8 w1 = *(const short8*)(Wdt + (wm * 64 + 32 + nrow) * KP + kt * 16 + hi8);
      if (kt == 0){
        oacc[0] = MFMA32(w0, b, zz);
        oacc[1] = MFMA32(w1, b, zz);
      } else {
        oacc[0] = MFMA32(w0, b, oacc[0]);
        oacc[1] = MFMA32(w1, b, oacc[1]);
      }
    }
    const int rowb = bbase + tile * NTILE + nrow;
    #pragma unroll
    for (int mt = 0; mt < 2; ++mt){
      #pragma unroll
      for (int q = 0; q < 4; ++q){
        float4_ v = {oacc[mt][4*q+0], oacc[mt][4*q+1],
                     oacc[mt][4*q+2], oacc[mt][4*q+3]};
        *(float4_*)&out[rowb * Dd + wm * 64 + mt * 32 + 8 * q + hi4] = v;
      }
    }
  }
}

extern "C" void kernel_launch(void* const* d_in, const int* in_sizes, int n_in,
                              void* d_out, int out_size, void* d_ws, size_t ws_size,
                              hipStream_t stream){
  const float* x0    = (const float*)d_in[0];
  const float* x1    = (const float*)d_in[1];
  const float* x2    = (const float*)d_in[2];
  const float* W_in  = (const float*)d_in[3];
  const float* U     = (const float*)d_in[4];
  const float* b_rnn = (const float*)d_in[5];
  const float* W_d   = (const float*)d_in[6];
  const float* b_d   = (const float*)d_in[7];

  unsigned short* Ut  = (unsigned short*)d_ws;
  unsigned short* Wdt = Ut + 256 * KP;
  float* out = (float*)d_out;

  build_tables<<<(2 * 256 * KP + 255) / 256, 256, 0, stream>>>(W_in, U, b_rnn, W_d, b_d, Ut, Wdt);
  rnn_main<<<Bsz / (2 * NTILE), THR, 0, stream>>>(x0, x1, x2, Ut, Wdt, out);
}

// Round 12
// 212.467 us; speedup vs baseline: 1.0942x; 1.0942x over previous
//
#include <hip/hip_runtime.h>
#include <hip/hip_bf16.h>
#include <stdint.h>

#define Bsz   16384
#define Tt    79
#define Hh    256
#define Dd    256
#define KP    272    // padded K: 256 h-cols + 3 x rows + 1 bias row + 12 zero pad
#define LROW  280    // LDS row stride in bf16 (560 B)
#define NTILE 32     // batch rows per block (2 blocks/CU)
#define THR   256    // 4 waves: wave w = m-quarter, each 64 m-cols x 32 n-rows

typedef __attribute__((ext_vector_type(8)))  short  short8;
typedef __attribute__((ext_vector_type(4)))  float  float4_;
typedef __attribute__((ext_vector_type(16))) float  float16_;

__device__ __forceinline__ unsigned short f2bf(float f){
  unsigned u = __float_as_uint(f);
  u += 0x7fffu + ((u >> 16) & 1u);      // RNE
  return (unsigned short)(u >> 16);
}
// HW packed f32x2 -> bf16x2 (RNE); no builtin on gfx950 (round-5: -11 us).
// Safe: single-cycle VALU op, no write-hazard window (unlike asm MFMA, which
// broke correctness in round 10 by bypassing compiler hazard management).
__device__ __forceinline__ unsigned pk2(float a, float b){
  unsigned r;
  asm("v_cvt_pk_bf16_f32 %0, %1, %2" : "=v"(r) : "v"(a), "v"(b));
  return r;
}

__global__ void build_tables(const float* __restrict__ W_in,
                             const float* __restrict__ U,
                             const float* __restrict__ b_rnn,
                             const float* __restrict__ W_d,
                             const float* __restrict__ b_d,
                             unsigned short* __restrict__ Ut,
                             unsigned short* __restrict__ Wdt){
  const int TBL = 256 * KP;
  int idx = blockIdx.x * 256 + threadIdx.x;
  if (idx >= 2 * TBL) return;
  int tb  = idx / TBL;
  int rem = idx - tb * TBL;
  int m = rem / KP;
  int k = rem - m * KP;
  float v = 0.f;
  if (tb == 0){
    if      (k < 256) v = U[k * 256 + m];
    else if (k < 259) v = W_in[(k - 256) * 256 + m];
    else if (k == 259) v = b_rnn[m];
  } else {
    if      (k < 256) v = W_d[k * 256 + m];
    else if (k == 259) v = b_d[m];
  }
  unsigned short o = f2bf(v);
  if (tb == 0) Ut[rem] = o; else Wdt[rem] = o;
}

// 512 blocks x 256 threads = 2 blocks/CU, 2 waves/SIMD (register wall: afr
// needs 136 regs/wave -> >2 waves/SIMD impossible; 1 wave/SIMD loses 25%).
// Step model (fits rounds 1-11): MFMA blocks its wave (no same-wave overlap),
// both waves serialize 68 MFMAs on the shared pipe (2196 cyc), tails + drain
// additive. Round-12: intrinsic MFMAs restored (round-10 asm MFMA broke
// correctness -- compiler hazard nops are mandatory); keep the x2 t-loop
// unroll (compile-time ping-pong, hoisted addressing, fewer predicates).
__global__ __launch_bounds__(THR, 2) void rnn_main(
    const float* __restrict__ x0,
    const float* __restrict__ x1,
    const float* __restrict__ x2,
    const unsigned short* __restrict__ Ut,
    const unsigned short* __restrict__ Wdt,
    float* __restrict__ out){
  __shared__ __align__(16) short hbuf[2][NTILE * LROW];

  const int tid  = threadIdx.x;
  const int lane = tid & 63;
  const int wm   = tid >> 6;        // m-quarter 0..3
  const int nrow = lane & 31;       // B operand / C col: batch row
  const int hi   = lane >> 5;       // k-half for A/B fragments
  const int hi8  = hi * 8;
  const int hi4  = hi * 4;
  const int bbase = blockIdx.x * NTILE;

  // ---- zero both LDS buffers (h0 = 0, pad rows = 0) ----
  {
    int4* p = (int4*)&hbuf[0][0];
    const int tot = 2 * NTILE * LROW * 2 / 16;
    int4 z = make_int4(0, 0, 0, 0);
    for (int i = tid; i < tot; i += THR) p[i] = z;
  }
  __syncthreads();

  // bias row (k=259) = 1.0 bf16 in BOTH buffers (never overwritten)
  if (tid < NTILE){
    hbuf[0][tid * LROW + 259] = (short)0x3F80;
    hbuf[1][tid * LROW + 259] = (short)0x3F80;
  }

  // x rows for step t=0 (original time index T-1) into buf 0
  const bool stager = (wm == 0) && (lane < NTILE);
  const int  sn  = lane & (NTILE - 1);
  const int  sgb = bbase + sn;
  if (stager){
    int tr = Tt - 1;
    float a = x0[sgb * Tt + tr];
    float b = x1[sgb * Tt + tr];
    float c = x2[sgb * Tt + tr];
    *(unsigned*)&hbuf[0][sn * LROW + 256] = pk2(a, b);
    hbuf[0][sn * LROW + 258] = (short)f2bf(c);
  }

  // ---- preload A fragments: 2 mt x 17 kt = 34 short8 (136 regs) ----
  short8 afr[2][17];
  #pragma unroll
  for (int mt = 0; mt < 2; ++mt){
    const unsigned short* p = Ut + (wm * 64 + mt * 32 + nrow) * KP + hi8;
    #pragma unroll
    for (int kt = 0; kt < 17; ++kt){
      afr[mt][kt] = *(const short8*)(p + kt * 16);
    }
  }

  __syncthreads();

  const float16_ zz = {0.f,0.f,0.f,0.f,0.f,0.f,0.f,0.f,
                       0.f,0.f,0.f,0.f,0.f,0.f,0.f,0.f};

  // one recurrence step: read HB, write HW; PRE: prefetch x for step T+1
  auto step = [&](const short* HB, short* HW, int T, bool PRE)
      __attribute__((always_inline)) {
    float xa = 0.f, xb = 0.f, xc = 0.f;
    if (PRE && stager){
      int tr = Tt - 2 - T;
      xa = x0[sgb * Tt + tr];
      xb = x1[sgb * Tt + tr];
      xc = x2[sgb * Tt + tr];
    }

    const short* rbase = HB + nrow * LROW + hi8;
    float16_ acc[2];

    __builtin_amdgcn_s_setprio(1);
    #pragma unroll
    for (int kt = 0; kt < 17; ++kt){
      short8 b = *(const short8*)(rbase + kt * 16);
      if (kt == 0){
        acc[0] = __builtin_amdgcn_mfma_f32_32x32x16_bf16(afr[0][0], b, zz, 0, 0, 0);
        acc[1] = __builtin_amdgcn_mfma_f32_32x32x16_bf16(afr[1][0], b, zz, 0, 0, 0);
      } else {
        acc[0] = __builtin_amdgcn_mfma_f32_32x32x16_bf16(afr[0][kt], b, acc[0], 0, 0, 0);
        acc[1] = __builtin_amdgcn_mfma_f32_32x32x16_bf16(afr[1][kt], b, acc[1], 0, 0, 0);
      }
    }
    __builtin_amdgcn_s_setprio(0);

    // relu + HW pack, write h(t+1).
    // C/D 32x32 layout: col=lane&31 (=nrow), row m = 8*q + 4*hi + (reg&3)
    #pragma unroll
    for (int mt = 0; mt < 2; ++mt){
      #pragma unroll
      for (int q = 0; q < 4; ++q){
        uint2 w;
        w.x = pk2(fmaxf(acc[mt][4*q+0], 0.f), fmaxf(acc[mt][4*q+1], 0.f));
        w.y = pk2(fmaxf(acc[mt][4*q+2], 0.f), fmaxf(acc[mt][4*q+3], 0.f));
        *(uint2*)&HW[nrow * LROW + wm * 64 + mt * 32 + 8 * q + hi4] = w;
      }
    }
    if (PRE && stager){
      *(unsigned*)&HW[sn * LROW + 256] = pk2(xa, xb);
      HW[sn * LROW + 258] = (short)f2bf(xc);
    }
    __syncthreads();
  };

  // ---- 79 steps, unrolled x2: ping-pong buffers are compile-time ----
  #pragma unroll 1
  for (int tp = 0; tp < 39; ++tp){
    step(&hbuf[0][0], &hbuf[1][0], 2 * tp,     true);   // t even: 0->1
    step(&hbuf[1][0], &hbuf[0][0], 2 * tp + 1, true);   // t odd : 1->0
  }
  step(&hbuf[0][0], &hbuf[1][0], 78, false);            // final step, no prefetch

  // ---- epilogue: out^T = W_d^T h^T + b_d; final h in buf[1] ----
  // (x rows in final buffer are stale but Wdt rows 256-258 are zero; bias row
  //  k=259 is 1.0 and Wdt[.,259] = b_d.)
  const short* hb = &hbuf[1][0];
  float16_ oacc[2];
  #pragma unroll
  for (int kt = 0; kt < 17; ++kt){
    short8 b  = *(const short8*)&hb[nrow * LROW + kt * 16 + hi8];
    short8 w0 = *(const short8*)(Wdt + (wm * 64 +  0 + nrow) * KP + kt * 16 + hi8);
    short8 w1 = *(const short8*)(Wdt + (wm * 64 + 32 + nrow) * KP + kt * 16 + hi8);
    if (kt == 0){
      oacc[0] = __builtin_amdgcn_mfma_f32_32x32x16_bf16(w0, b, zz, 0, 0, 0);
      oacc[1] = __builtin_amdgcn_mfma_f32_32x32x16_bf16(w1, b, zz, 0, 0, 0);
    } else {
      oacc[0] = __builtin_amdgcn_mfma_f32_32x32x16_bf16(w0, b, oacc[0], 0, 0, 0);
      oacc[1] = __builtin_amdgcn_mfma_f32_32x32x16_bf16(w1, b, oacc[1], 0, 0, 0);
    }
  }

  #pragma unroll
  for (int mt = 0; mt < 2; ++mt){
    #pragma unroll
    for (int q = 0; q < 4; ++q){
      float4_ v = {oacc[mt][4*q+0], oacc[mt][4*q+1],
                   oacc[mt][4*q+2], oacc[mt][4*q+3]};
      *(float4_*)&out[(bbase + nrow) * Dd + wm * 64 + mt * 32 + 8 * q + hi4] = v;
    }
  }
}

extern "C" void kernel_launch(void* const* d_in, const int* in_sizes, int n_in,
                              void* d_out, int out_size, void* d_ws, size_t ws_size,
                              hipStream_t stream){
  const float* x0    = (const float*)d_in[0];
  const float* x1    = (const float*)d_in[1];
  const float* x2    = (const float*)d_in[2];
  const float* W_in  = (const float*)d_in[3];
  const float* U     = (const float*)d_in[4];
  const float* b_rnn = (const float*)d_in[5];
  const float* W_d   = (const float*)d_in[6];
  const float* b_d   = (const float*)d_in[7];

  unsigned short* Ut  = (unsigned short*)d_ws;
  unsigned short* Wdt = Ut + 256 * KP;
  float* out = (float*)d_out;

  build_tables<<<(2 * 256 * KP + 255) / 256, 256, 0, stream>>>(W_in, U, b_rnn, W_d, b_d, Ut, Wdt);
  rnn_main<<<Bsz / NTILE, THR, 0, stream>>>(x0, x1, x2, Ut, Wdt, out);
}